// Round 11
// baseline (335.699 us; speedup 1.0000x reference)
//
#include <hip/hip_runtime.h>
#include <hip/hip_bf16.h>

// DRew-GIN: N=50000, E=800000, D=128, L=3, NU=1.
// R11: column-split gather — each gather runs as 2 serialized half-column
//      passes (128B line per edge per pass) so the pass working set (6.4MB)
//      better fits per-XCD L2. 8-lane groups, 4-deep uint4 pipeline.

#define NODES 50000
#define EDGES 800000
#define DIM   128
#define ND    ((long)NODES * DIM)
#define NB3   (3 * NODES)            // buckets: d*3 + (k-1)
#define NPART 4
#define PSIZE (NODES / NPART)        // 12500
#define NROWP 50048
#define NBLKS ((NB3 + 255) / 256)    // 587
#define NCELL 96                     // 3 km1 * 32 size classes
#define SORTN (NCELL * NBLKS)

typedef __attribute__((ext_vector_type(8))) short  bf16x8;
typedef __attribute__((ext_vector_type(4))) float  f32x4;

#define LDS_STRIDE 136   // bf16 elements; 272B rows

// ---------------------------------------------------------------------------
__global__ __launch_bounds__(256) void init_kernel(
    const float* __restrict__ x, const float* __restrict__ Ws,
    const float* __restrict__ Wk, __hip_bfloat16* __restrict__ xb0,
    __hip_bfloat16* __restrict__ xb1, __hip_bfloat16* __restrict__ xb2,
    __hip_bfloat16* __restrict__ WT, int* __restrict__ cursor) {
  int b = blockIdx.x, tid = threadIdx.x;
  long i = (long)b * 256 + tid;
  if (i < ND / 4) {
    float4 v = ((const float4*)x)[i];
    union { __hip_bfloat16 h[4]; uint2 u; } pk;
    pk.h[0] = __float2bfloat16(v.x); pk.h[1] = __float2bfloat16(v.y);
    pk.h[2] = __float2bfloat16(v.z); pk.h[3] = __float2bfloat16(v.w);
    ((uint2*)xb0)[i] = pk.u;
  }
  if (b < 12) {
    const float* src = (b < 3) ? (Ws + (long)b * 16384) : (Wk + (long)(b - 3) * 16384);
    __hip_bfloat16* dst = WT + (long)b * 16384;
    for (int idx = tid; idx < 16384; idx += 256) {
      int k = idx >> 7, n = idx & 127;
      dst[n * 128 + k] = __float2bfloat16(src[idx]);
    }
  }
  if (b >= 12 && b < 12 + NBLKS) {
    int g = (b - 12) * 256 + tid;
    if (g < NB3) cursor[g] = 0;
  }
  if (b == 599 && tid < DIM) {
    xb0[(long)NODES * DIM + tid] = __float2bfloat16(0.f);
    xb1[(long)NODES * DIM + tid] = __float2bfloat16(0.f);
    xb2[(long)NODES * DIM + tid] = __float2bfloat16(0.f);
  }
}

// ---------------------------------------------------------------------------
// CSR build (pad-to-4).
__global__ __launch_bounds__(256) void hist_kernel(
    const int* __restrict__ ei, const int* __restrict__ attr,
    int* __restrict__ counts, int E) {
  int e = blockIdx.x * 256 + threadIdx.x;
  if (e >= E) return;
  atomicAdd(&counts[ei[E + e] * 3 + (attr[e] - 1)], 1);
}

__global__ __launch_bounds__(256) void scan_a_kernel(
    const int* __restrict__ counts, int* __restrict__ partial,
    int* __restrict__ blocksums, int n) {
  __shared__ int tmp[256];
  int gid = blockIdx.x * 256 + threadIdx.x;
  int v = (gid < n) ? ((counts[gid] + 3) & ~3) : 0;
  tmp[threadIdx.x] = v;
  __syncthreads();
  for (int off = 1; off < 256; off <<= 1) {
    int t = (threadIdx.x >= off) ? tmp[threadIdx.x - off] : 0;
    __syncthreads();
    tmp[threadIdx.x] += t;
    __syncthreads();
  }
  if (gid < n) partial[gid] = tmp[threadIdx.x] - v;
  if (threadIdx.x == 255) blocksums[blockIdx.x] = tmp[255];
}

__global__ __launch_bounds__(256) void scan_b_kernel(int* __restrict__ bs, int nb) {
  __shared__ int tmp[256];
  __shared__ int carry;
  if (threadIdx.x == 0) carry = 0;
  __syncthreads();
  for (int base = 0; base < nb; base += 256) {
    int gid = base + threadIdx.x;
    int v = (gid < nb) ? bs[gid] : 0;
    tmp[threadIdx.x] = v;
    __syncthreads();
    for (int off = 1; off < 256; off <<= 1) {
      int t = (threadIdx.x >= off) ? tmp[threadIdx.x - off] : 0;
      __syncthreads();
      tmp[threadIdx.x] += t;
      __syncthreads();
    }
    if (gid < nb) bs[gid] = tmp[threadIdx.x] - v + carry;
    __syncthreads();
    if (threadIdx.x == 0) carry += tmp[255];
    __syncthreads();
  }
}

// scan_c + sort histogram fused.
__global__ __launch_bounds__(256) void scanc_bhist_kernel(
    int* __restrict__ rowptr, int* __restrict__ cursor,
    const int* __restrict__ bs, int* __restrict__ csr,
    int* __restrict__ G, int n) {
  __shared__ int h[NCELL];
  if (threadIdx.x < NCELL) h[threadIdx.x] = 0;
  __syncthreads();
  int gid = blockIdx.x * 256 + threadIdx.x;
  if (gid < n) {
    int cnt = cursor[gid];
    int pcnt = (cnt + 3) & ~3;
    int val = rowptr[gid] + bs[blockIdx.x];
    rowptr[gid] = val;
    cursor[gid] = val;
    for (int i = cnt; i < pcnt; ++i) csr[val + i] = NODES;
    if (gid == n - 1) rowptr[n] = val + pcnt;
    int c = pcnt >> 2; if (c > 31) c = 31;
    int km1 = gid - (gid / 3) * 3;
    atomicAdd(&h[km1 * 32 + (31 - c)], 1);
  }
  __syncthreads();
  if (threadIdx.x < NCELL) G[threadIdx.x * NBLKS + blockIdx.x] = h[threadIdx.x];
}

__global__ __launch_bounds__(256) void fill_kernel(
    const int* __restrict__ ei, const int* __restrict__ attr,
    int* __restrict__ cursor, int* __restrict__ csr_src, int E) {
  int p = blockIdx.x & (NPART - 1);
  int chunk = blockIdx.x >> 2;
  int e = chunk * 256 + threadIdx.x;
  if (e >= E) return;
  int d = ei[E + e];
  int lo = p * PSIZE;
  if (d < lo || d >= lo + PSIZE) return;
  int pos = atomicAdd(&cursor[d * 3 + (attr[e] - 1)], 1);
  csr_src[pos] = ei[e];
}

__global__ __launch_bounds__(256) void fscan_a_kernel(
    const int* __restrict__ in, int* __restrict__ partial,
    int* __restrict__ blocksums, int n) {
  __shared__ int tmp[256];
  int gid = blockIdx.x * 256 + threadIdx.x;
  int v = (gid < n) ? in[gid] : 0;
  tmp[threadIdx.x] = v;
  __syncthreads();
  for (int off = 1; off < 256; off <<= 1) {
    int t = (threadIdx.x >= off) ? tmp[threadIdx.x - off] : 0;
    __syncthreads();
    tmp[threadIdx.x] += t;
    __syncthreads();
  }
  if (gid < n) partial[gid] = tmp[threadIdx.x] - v;
  if (threadIdx.x == 255) blocksums[blockIdx.x] = tmp[255];
}

__global__ __launch_bounds__(256) void bfill_kernel(
    const int* __restrict__ rowptr, const int* __restrict__ G,
    const int* __restrict__ bsum2, int* __restrict__ wl) {
  __shared__ int base[NCELL];
  if (threadIdx.x < NCELL) {
    int gidx = threadIdx.x * NBLKS + blockIdx.x;
    base[threadIdx.x] = G[gidx] + bsum2[gidx >> 8];
  }
  __syncthreads();
  int b = blockIdx.x * 256 + threadIdx.x;
  if (b >= NB3) return;
  int pcnt = rowptr[b + 1] - rowptr[b];
  int c = pcnt >> 2; if (c > 31) c = 31;
  int km1 = b - (b / 3) * 3;
  int pos = atomicAdd(&base[km1 * 32 + (31 - c)], 1);
  wl[pos] = b;
}

// ---------------------------------------------------------------------------
// Gather, half-column pass: 8 lanes/row-half (one 128B line per edge),
// colOfs in {0, 64}. Single source tensor; km1 selects output buffer.
__global__ __launch_bounds__(256, 6) void gather_kernel(
    const __hip_bfloat16* __restrict__ src,
    const int* __restrict__ rowptr, const int* __restrict__ csr,
    const int* __restrict__ wl,
    __hip_bfloat16* __restrict__ ag0, __hip_bfloat16* __restrict__ ag1,
    __hip_bfloat16* __restrict__ ag2, int nwork, int colOfs) {
  int group = (blockIdx.x * 256 + threadIdx.x) >> 3;
  int lane8 = threadIdx.x & 7;
  if (group >= nwork) return;
  int b = wl[group];
  int d = b / 3;
  int km1 = b - d * 3;
  __hip_bfloat16* ag = (km1 == 0) ? ag0 : ((km1 == 1) ? ag1 : ag2);
  const __hip_bfloat16* sp = src + colOfs + lane8 * 8;
  int beg = rowptr[b], end = rowptr[b + 1];   // (end-beg)%4 == 0
  float a0 = 0.f, a1 = 0.f, a2 = 0.f, a3 = 0.f,
        a4 = 0.f, a5 = 0.f, a6 = 0.f, a7 = 0.f;
  for (int base = beg; base < end; base += 8) {
    int idxv = csr[base + lane8];             // slack-allocated
    int cnt = end - base; if (cnt > 8) cnt = 8;   // multiple of 4
    for (int j = 0; j < cnt; j += 4) {
      int q0 = __shfl(idxv, j + 0, 8);
      int q1 = __shfl(idxv, j + 1, 8);
      int q2 = __shfl(idxv, j + 2, 8);
      int q3 = __shfl(idxv, j + 3, 8);
      uint4 v0 = *(const uint4*)(sp + (long)q0 * DIM);
      uint4 v1 = *(const uint4*)(sp + (long)q1 * DIM);
      uint4 v2 = *(const uint4*)(sp + (long)q2 * DIM);
      uint4 v3 = *(const uint4*)(sp + (long)q3 * DIM);
      a0 += __uint_as_float(v0.x << 16) + __uint_as_float(v1.x << 16)
          + __uint_as_float(v2.x << 16) + __uint_as_float(v3.x << 16);
      a1 += __uint_as_float(v0.x & 0xffff0000u) + __uint_as_float(v1.x & 0xffff0000u)
          + __uint_as_float(v2.x & 0xffff0000u) + __uint_as_float(v3.x & 0xffff0000u);
      a2 += __uint_as_float(v0.y << 16) + __uint_as_float(v1.y << 16)
          + __uint_as_float(v2.y << 16) + __uint_as_float(v3.y << 16);
      a3 += __uint_as_float(v0.y & 0xffff0000u) + __uint_as_float(v1.y & 0xffff0000u)
          + __uint_as_float(v2.y & 0xffff0000u) + __uint_as_float(v3.y & 0xffff0000u);
      a4 += __uint_as_float(v0.z << 16) + __uint_as_float(v1.z << 16)
          + __uint_as_float(v2.z << 16) + __uint_as_float(v3.z << 16);
      a5 += __uint_as_float(v0.z & 0xffff0000u) + __uint_as_float(v1.z & 0xffff0000u)
          + __uint_as_float(v2.z & 0xffff0000u) + __uint_as_float(v3.z & 0xffff0000u);
      a6 += __uint_as_float(v0.w << 16) + __uint_as_float(v1.w << 16)
          + __uint_as_float(v2.w << 16) + __uint_as_float(v3.w << 16);
      a7 += __uint_as_float(v0.w & 0xffff0000u) + __uint_as_float(v1.w & 0xffff0000u)
          + __uint_as_float(v2.w & 0xffff0000u) + __uint_as_float(v3.w & 0xffff0000u);
    }
  }
  union { __hip_bfloat16 h[8]; uint4 u; } pk;
  pk.h[0] = __float2bfloat16(a0); pk.h[1] = __float2bfloat16(a1);
  pk.h[2] = __float2bfloat16(a2); pk.h[3] = __float2bfloat16(a3);
  pk.h[4] = __float2bfloat16(a4); pk.h[5] = __float2bfloat16(a5);
  pk.h[6] = __float2bfloat16(a6); pk.h[7] = __float2bfloat16(a7);
  *(uint4*)(ag + (long)d * DIM + colOfs + lane8 * 8) = pk.u;
}

// ---------------------------------------------------------------------------
// Layer GEMM: bf16 node state, A-frags direct from global, B in LDS.
__global__ __launch_bounds__(256, 4) void lgemm_kernel(
    const __hip_bfloat16* __restrict__ xbSelf,
    const __hip_bfloat16* __restrict__ ag0,
    const __hip_bfloat16* __restrict__ ag1,
    const __hip_bfloat16* __restrict__ ag2,
    const __hip_bfloat16* __restrict__ WT,
    const float* __restrict__ bs_t,
    const float* __restrict__ bk_t,
    const float* __restrict__ epsp,
    __hip_bfloat16* __restrict__ xnb,
    float* __restrict__ xn,
    int t) {
  __shared__ __hip_bfloat16 b_lds[128 * LDS_STRIDE];  // 34816 B

  int tid = threadIdx.x;
  long row0 = (long)blockIdx.x * 64;
  int wave = tid >> 6, lane = tid & 63;
  int l15 = lane & 15, q = lane >> 4;
  long arow = row0 + wave * 16 + l15;

  const __hip_bfloat16* Asrc[4] = {xbSelf, ag0, ag1, ag2};
  f32x4 out[8];

  for (int p = 0; p <= t + 1; ++p) {
    if (p > 0) __syncthreads();
    const __hip_bfloat16* Am = Asrc[p];
    uint4 af[4];
#pragma unroll
    for (int k0i = 0; k0i < 4; ++k0i)
      af[k0i] = *(const uint4*)(Am + arow * DIM + k0i * 32 + 8 * q);
    const __hip_bfloat16* W = (p == 0) ? (WT + (long)t * 16384)
                                       : (WT + (long)(3 + t * 3 + (p - 1)) * 16384);
    {
      const uint4* bq = (const uint4*)W;
#pragma unroll
      for (int i = 0; i < 8; ++i) {
        int idx = tid + 256 * i;
        int n = idx >> 4, k8 = idx & 15;
        uint4 v = bq[idx];
        *(uint4*)(b_lds + n * LDS_STRIDE + k8 * 8) = v;
      }
    }
    __syncthreads();

    f32x4 acc[8] = {};
#pragma unroll
    for (int k0i = 0; k0i < 4; ++k0i) {
      bf16x8 a = __builtin_bit_cast(bf16x8, af[k0i]);
#pragma unroll
      for (int j = 0; j < 8; ++j) {
        bf16x8 bfr = *(const bf16x8*)(b_lds + (16 * j + l15) * LDS_STRIDE + k0i * 32 + 8 * q);
        acc[j] = __builtin_amdgcn_mfma_f32_16x16x32_bf16(a, bfr, acc[j], 0, 0, 0);
      }
    }
    if (p == 0) {
      float sc = 1.0f + *epsp;
#pragma unroll
      for (int j = 0; j < 8; ++j) {
        float b = bs_t[16 * j + l15];
#pragma unroll
        for (int r = 0; r < 4; ++r) out[j][r] = sc * fmaxf(acc[j][r] + b, 0.f);
      }
    } else {
      const float* bb = bk_t + (p - 1) * 128;
#pragma unroll
      for (int j = 0; j < 8; ++j) {
        float b = bb[16 * j + l15];
#pragma unroll
        for (int r = 0; r < 4; ++r) out[j][r] += fmaxf(acc[j][r] + b, 0.f);
      }
    }
  }

  long rbase = row0 + wave * 16 + q * 4;
  bool fin = (xn != nullptr);
#pragma unroll
  for (int j = 0; j < 8; ++j) {
    int col = 16 * j + l15;
#pragma unroll
    for (int r = 0; r < 4; ++r) {
      long grow = rbase + r;
      if (grow < NODES) {
        float res = __bfloat162float(xbSelf[grow * DIM + col]);
        float v = res + fmaxf(out[j][r], 0.f);
        if (fin) xn[grow * DIM + col] = v;
        else     xnb[grow * DIM + col] = __float2bfloat16(v);
      }
    }
  }
}

// ---------------------------------------------------------------------------
extern "C" void kernel_launch(void* const* d_in, const int* in_sizes, int n_in,
                              void* d_out, int out_size, void* d_ws, size_t ws_size,
                              hipStream_t stream) {
  const float* x    = (const float*)d_in[0];
  const int*   ei   = (const int*)d_in[1];
  const int*   attr = (const int*)d_in[2];
  const float* Ws   = (const float*)d_in[3];
  const float* bs   = (const float*)d_in[4];
  const float* Wk   = (const float*)d_in[5];
  const float* bk   = (const float*)d_in[6];
  const float* eps  = (const float*)d_in[7];
  float* out = (float*)d_out;

  char* ws = (char*)d_ws;
  size_t off = 0;
  auto alloc = [&](size_t bytes) { char* p = ws + off; off += (bytes + 255) & ~(size_t)255; return p; };
  const size_t ROWB = (size_t)NROWP * DIM * 2;
  __hip_bfloat16* xb0  = (__hip_bfloat16*)alloc(ROWB);
  __hip_bfloat16* xb1  = (__hip_bfloat16*)alloc(ROWB);
  __hip_bfloat16* xb2  = (__hip_bfloat16*)alloc(ROWB);
  __hip_bfloat16* agA0 = (__hip_bfloat16*)alloc(ROWB);
  __hip_bfloat16* agA1 = (__hip_bfloat16*)alloc(ROWB);
  __hip_bfloat16* agA2 = (__hip_bfloat16*)alloc(ROWB);
  __hip_bfloat16* agB0 = (__hip_bfloat16*)alloc(ROWB);
  __hip_bfloat16* agB1 = (__hip_bfloat16*)alloc(ROWB);
  __hip_bfloat16* agC0 = (__hip_bfloat16*)alloc(ROWB);
  __hip_bfloat16* WT   = (__hip_bfloat16*)alloc(12 * 16384 * 2);
  int* cursor    = (int*)alloc((size_t)NB3 * 4);
  int* rowptr    = (int*)alloc((size_t)(NB3 + 1) * 4);
  int* blocksums = (int*)alloc(1024 * 4);
  int* G         = (int*)alloc((size_t)SORTN * 4);
  int* bsum2     = (int*)alloc(1024 * 4);
  int* wl        = (int*)alloc((size_t)NB3 * 4);
  int* csr_src   = (int*)alloc((size_t)(EDGES + 4 * NB3 + 16) * 4);

  int egrid  = (EDGES + 255) / 256;        // 3125
  int igrid  = (int)(ND / 4 / 256);        // 6250
  int fgrid  = (SORTN + 255) / 256;        // 221

  hipLaunchKernelGGL(init_kernel, dim3(igrid), dim3(256), 0, stream,
                     x, Ws, Wk, xb0, xb1, xb2, WT, cursor);
  hipLaunchKernelGGL(hist_kernel, dim3(egrid), dim3(256), 0, stream, ei, attr, cursor, EDGES);
  hipLaunchKernelGGL(scan_a_kernel, dim3(NBLKS), dim3(256), 0, stream, cursor, rowptr, blocksums, NB3);
  hipLaunchKernelGGL(scan_b_kernel, dim3(1), dim3(256), 0, stream, blocksums, NBLKS);
  hipLaunchKernelGGL(scanc_bhist_kernel, dim3(NBLKS), dim3(256), 0, stream,
                     rowptr, cursor, blocksums, csr_src, G, NB3);
  hipLaunchKernelGGL(fill_kernel, dim3(egrid * NPART), dim3(256), 0, stream, ei, attr, cursor, csr_src, EDGES);
  hipLaunchKernelGGL(fscan_a_kernel, dim3(fgrid), dim3(256), 0, stream, G, G, bsum2, SORTN);
  hipLaunchKernelGGL(scan_b_kernel, dim3(1), dim3(256), 0, stream, bsum2, fgrid);
  hipLaunchKernelGGL(bfill_kernel, dim3(NBLKS), dim3(256), 0, stream, rowptr, G, bsum2, wl);

  int ggrid = (NODES + 63) / 64;
  auto glaunch = [&](int nwork, const __hip_bfloat16* src, __hip_bfloat16* a0,
                     __hip_bfloat16* a1, __hip_bfloat16* a2) {
    int blocks = (nwork * 8 + 255) / 256;
    hipLaunchKernelGGL(gather_kernel, dim3(blocks), dim3(256), 0, stream,
                       src, rowptr, csr_src, wl, a0, a1, a2, nwork, 0);
    hipLaunchKernelGGL(gather_kernel, dim3(blocks), dim3(256), 0, stream,
                       src, rowptr, csr_src, wl, a0, a1, a2, nwork, 64);
  };

  // Gather A: all buckets from xb0.
  glaunch(3 * NODES, xb0, agA0, agA1, agA2);
  // Layer 0
  hipLaunchKernelGGL(lgemm_kernel, dim3(ggrid), dim3(256), 0, stream,
                     xb0, agA0, agA0, agA0, WT, bs + 0, bk + 0, eps + 0,
                     xb1, (float*)nullptr, 0);
  // Gather B: km1 in {0,1} from xb1.
  glaunch(2 * NODES, xb1, agB0, agB1, agB1);
  // Layer 1
  hipLaunchKernelGGL(lgemm_kernel, dim3(ggrid), dim3(256), 0, stream,
                     xb1, agB0, agA1, agA1, WT, bs + 128, bk + 3 * 128, eps + 1,
                     xb2, (float*)nullptr, 1);
  // Gather C: km1=0 from xb2.
  glaunch(NODES, xb2, agC0, agC0, agC0);
  // Layer 2
  hipLaunchKernelGGL(lgemm_kernel, dim3(ggrid), dim3(256), 0, stream,
                     xb2, agC0, agB1, agA2, WT, bs + 256, bk + 6 * 128, eps + 2,
                     (__hip_bfloat16*)nullptr, out, 2);
}

// Round 12
// 330.643 us; speedup vs baseline: 1.0153x; 1.0153x over previous
//
#include <hip/hip_runtime.h>
#include <hip/hip_bf16.h>

// DRew-GIN: N=50000, E=800000, D=128, L=3, NU=1.
// R12: R10 structure (source-major single-source gathers, 16-lane groups,
//      degree-sorted worklist) + non-temporal ag stores (keep L2 for the
//      random gather reads; ag re-read is streaming-tolerant).

#define NODES 50000
#define EDGES 800000
#define DIM   128
#define ND    ((long)NODES * DIM)
#define NB3   (3 * NODES)            // buckets: d*3 + (k-1)
#define NPART 4
#define PSIZE (NODES / NPART)        // 12500
#define NROWP 50048
#define NBLKS ((NB3 + 255) / 256)    // 587
#define NCELL 96                     // 3 km1 * 32 size classes
#define SORTN (NCELL * NBLKS)

typedef __attribute__((ext_vector_type(8))) short  bf16x8;
typedef __attribute__((ext_vector_type(4))) float  f32x4;
typedef __attribute__((ext_vector_type(4))) unsigned int u32x4;

#define LDS_STRIDE 136   // bf16 elements; 272B rows

// ---------------------------------------------------------------------------
__global__ __launch_bounds__(256) void init_kernel(
    const float* __restrict__ x, const float* __restrict__ Ws,
    const float* __restrict__ Wk, __hip_bfloat16* __restrict__ xb0,
    __hip_bfloat16* __restrict__ xb1, __hip_bfloat16* __restrict__ xb2,
    __hip_bfloat16* __restrict__ WT, int* __restrict__ cursor) {
  int b = blockIdx.x, tid = threadIdx.x;
  long i = (long)b * 256 + tid;
  if (i < ND / 4) {
    float4 v = ((const float4*)x)[i];
    union { __hip_bfloat16 h[4]; uint2 u; } pk;
    pk.h[0] = __float2bfloat16(v.x); pk.h[1] = __float2bfloat16(v.y);
    pk.h[2] = __float2bfloat16(v.z); pk.h[3] = __float2bfloat16(v.w);
    ((uint2*)xb0)[i] = pk.u;
  }
  if (b < 12) {
    const float* src = (b < 3) ? (Ws + (long)b * 16384) : (Wk + (long)(b - 3) * 16384);
    __hip_bfloat16* dst = WT + (long)b * 16384;
    for (int idx = tid; idx < 16384; idx += 256) {
      int k = idx >> 7, n = idx & 127;
      dst[n * 128 + k] = __float2bfloat16(src[idx]);
    }
  }
  if (b >= 12 && b < 12 + NBLKS) {
    int g = (b - 12) * 256 + tid;
    if (g < NB3) cursor[g] = 0;
  }
  if (b == 599 && tid < DIM) {
    xb0[(long)NODES * DIM + tid] = __float2bfloat16(0.f);
    xb1[(long)NODES * DIM + tid] = __float2bfloat16(0.f);
    xb2[(long)NODES * DIM + tid] = __float2bfloat16(0.f);
  }
}

// ---------------------------------------------------------------------------
// CSR build (pad-to-4).
__global__ __launch_bounds__(256) void hist_kernel(
    const int* __restrict__ ei, const int* __restrict__ attr,
    int* __restrict__ counts, int E) {
  int e = blockIdx.x * 256 + threadIdx.x;
  if (e >= E) return;
  atomicAdd(&counts[ei[E + e] * 3 + (attr[e] - 1)], 1);
}

__global__ __launch_bounds__(256) void scan_a_kernel(
    const int* __restrict__ counts, int* __restrict__ partial,
    int* __restrict__ blocksums, int n) {
  __shared__ int tmp[256];
  int gid = blockIdx.x * 256 + threadIdx.x;
  int v = (gid < n) ? ((counts[gid] + 3) & ~3) : 0;
  tmp[threadIdx.x] = v;
  __syncthreads();
  for (int off = 1; off < 256; off <<= 1) {
    int t = (threadIdx.x >= off) ? tmp[threadIdx.x - off] : 0;
    __syncthreads();
    tmp[threadIdx.x] += t;
    __syncthreads();
  }
  if (gid < n) partial[gid] = tmp[threadIdx.x] - v;
  if (threadIdx.x == 255) blocksums[blockIdx.x] = tmp[255];
}

__global__ __launch_bounds__(256) void scan_b_kernel(int* __restrict__ bs, int nb) {
  __shared__ int tmp[256];
  __shared__ int carry;
  if (threadIdx.x == 0) carry = 0;
  __syncthreads();
  for (int base = 0; base < nb; base += 256) {
    int gid = base + threadIdx.x;
    int v = (gid < nb) ? bs[gid] : 0;
    tmp[threadIdx.x] = v;
    __syncthreads();
    for (int off = 1; off < 256; off <<= 1) {
      int t = (threadIdx.x >= off) ? tmp[threadIdx.x - off] : 0;
      __syncthreads();
      tmp[threadIdx.x] += t;
      __syncthreads();
    }
    if (gid < nb) bs[gid] = tmp[threadIdx.x] - v + carry;
    __syncthreads();
    if (threadIdx.x == 0) carry += tmp[255];
    __syncthreads();
  }
}

// scan_c + sort histogram fused. cell = km1*32 + (31 - min(pcnt/4,31)).
__global__ __launch_bounds__(256) void scanc_bhist_kernel(
    int* __restrict__ rowptr, int* __restrict__ cursor,
    const int* __restrict__ bs, int* __restrict__ csr,
    int* __restrict__ G, int n) {
  __shared__ int h[NCELL];
  if (threadIdx.x < NCELL) h[threadIdx.x] = 0;
  __syncthreads();
  int gid = blockIdx.x * 256 + threadIdx.x;
  if (gid < n) {
    int cnt = cursor[gid];
    int pcnt = (cnt + 3) & ~3;
    int val = rowptr[gid] + bs[blockIdx.x];
    rowptr[gid] = val;
    cursor[gid] = val;
    for (int i = cnt; i < pcnt; ++i) csr[val + i] = NODES;
    if (gid == n - 1) rowptr[n] = val + pcnt;
    int c = pcnt >> 2; if (c > 31) c = 31;
    int km1 = gid - (gid / 3) * 3;
    atomicAdd(&h[km1 * 32 + (31 - c)], 1);
  }
  __syncthreads();
  if (threadIdx.x < NCELL) G[threadIdx.x * NBLKS + blockIdx.x] = h[threadIdx.x];
}

__global__ __launch_bounds__(256) void fill_kernel(
    const int* __restrict__ ei, const int* __restrict__ attr,
    int* __restrict__ cursor, int* __restrict__ csr_src, int E) {
  int p = blockIdx.x & (NPART - 1);
  int chunk = blockIdx.x >> 2;
  int e = chunk * 256 + threadIdx.x;
  if (e >= E) return;
  int d = ei[E + e];
  int lo = p * PSIZE;
  if (d < lo || d >= lo + PSIZE) return;
  int pos = atomicAdd(&cursor[d * 3 + (attr[e] - 1)], 1);
  csr_src[pos] = ei[e];
}

__global__ __launch_bounds__(256) void fscan_a_kernel(
    const int* __restrict__ in, int* __restrict__ partial,
    int* __restrict__ blocksums, int n) {
  __shared__ int tmp[256];
  int gid = blockIdx.x * 256 + threadIdx.x;
  int v = (gid < n) ? in[gid] : 0;
  tmp[threadIdx.x] = v;
  __syncthreads();
  for (int off = 1; off < 256; off <<= 1) {
    int t = (threadIdx.x >= off) ? tmp[threadIdx.x - off] : 0;
    __syncthreads();
    tmp[threadIdx.x] += t;
    __syncthreads();
  }
  if (gid < n) partial[gid] = tmp[threadIdx.x] - v;
  if (threadIdx.x == 255) blocksums[blockIdx.x] = tmp[255];
}

__global__ __launch_bounds__(256) void bfill_kernel(
    const int* __restrict__ rowptr, const int* __restrict__ G,
    const int* __restrict__ bsum2, int* __restrict__ wl) {
  __shared__ int base[NCELL];
  if (threadIdx.x < NCELL) {
    int gidx = threadIdx.x * NBLKS + blockIdx.x;
    base[threadIdx.x] = G[gidx] + bsum2[gidx >> 8];
  }
  __syncthreads();
  int b = blockIdx.x * 256 + threadIdx.x;
  if (b >= NB3) return;
  int pcnt = rowptr[b + 1] - rowptr[b];
  int c = pcnt >> 2; if (c > 31) c = 31;
  int km1 = b - (b / 3) * 3;
  int pos = atomicAdd(&base[km1 * 32 + (31 - c)], 1);
  wl[pos] = b;
}

// ---------------------------------------------------------------------------
// Gather: SINGLE source tensor; 16 lanes/row, 4-deep uint4 pipeline.
// ag output written non-temporally (keep L2 for the random reads).
__global__ __launch_bounds__(256, 6) void gather_kernel(
    const __hip_bfloat16* __restrict__ src,
    const int* __restrict__ rowptr, const int* __restrict__ csr,
    const int* __restrict__ wl,
    __hip_bfloat16* __restrict__ ag0, __hip_bfloat16* __restrict__ ag1,
    __hip_bfloat16* __restrict__ ag2, int nwork) {
  int group = (blockIdx.x * 256 + threadIdx.x) >> 4;
  int lane16 = threadIdx.x & 15;
  if (group >= nwork) return;
  int b = wl[group];
  int d = b / 3;
  int km1 = b - d * 3;
  __hip_bfloat16* ag = (km1 == 0) ? ag0 : ((km1 == 1) ? ag1 : ag2);
  int beg = rowptr[b], end = rowptr[b + 1];   // (end-beg)%4 == 0
  float a0 = 0.f, a1 = 0.f, a2 = 0.f, a3 = 0.f,
        a4 = 0.f, a5 = 0.f, a6 = 0.f, a7 = 0.f;
  for (int base = beg; base < end; base += 16) {
    int idxv = csr[base + lane16];            // slack-allocated
    int cnt = end - base; if (cnt > 16) cnt = 16;
    for (int j = 0; j < cnt; j += 4) {
      int q0 = __shfl(idxv, j + 0, 16);
      int q1 = __shfl(idxv, j + 1, 16);
      int q2 = __shfl(idxv, j + 2, 16);
      int q3 = __shfl(idxv, j + 3, 16);
      uint4 v0 = *(const uint4*)(src + (long)q0 * DIM + lane16 * 8);
      uint4 v1 = *(const uint4*)(src + (long)q1 * DIM + lane16 * 8);
      uint4 v2 = *(const uint4*)(src + (long)q2 * DIM + lane16 * 8);
      uint4 v3 = *(const uint4*)(src + (long)q3 * DIM + lane16 * 8);
      a0 += __uint_as_float(v0.x << 16) + __uint_as_float(v1.x << 16)
          + __uint_as_float(v2.x << 16) + __uint_as_float(v3.x << 16);
      a1 += __uint_as_float(v0.x & 0xffff0000u) + __uint_as_float(v1.x & 0xffff0000u)
          + __uint_as_float(v2.x & 0xffff0000u) + __uint_as_float(v3.x & 0xffff0000u);
      a2 += __uint_as_float(v0.y << 16) + __uint_as_float(v1.y << 16)
          + __uint_as_float(v2.y << 16) + __uint_as_float(v3.y << 16);
      a3 += __uint_as_float(v0.y & 0xffff0000u) + __uint_as_float(v1.y & 0xffff0000u)
          + __uint_as_float(v2.y & 0xffff0000u) + __uint_as_float(v3.y & 0xffff0000u);
      a4 += __uint_as_float(v0.z << 16) + __uint_as_float(v1.z << 16)
          + __uint_as_float(v2.z << 16) + __uint_as_float(v3.z << 16);
      a5 += __uint_as_float(v0.z & 0xffff0000u) + __uint_as_float(v1.z & 0xffff0000u)
          + __uint_as_float(v2.z & 0xffff0000u) + __uint_as_float(v3.z & 0xffff0000u);
      a6 += __uint_as_float(v0.w << 16) + __uint_as_float(v1.w << 16)
          + __uint_as_float(v2.w << 16) + __uint_as_float(v3.w << 16);
      a7 += __uint_as_float(v0.w & 0xffff0000u) + __uint_as_float(v1.w & 0xffff0000u)
          + __uint_as_float(v2.w & 0xffff0000u) + __uint_as_float(v3.w & 0xffff0000u);
    }
  }
  union { __hip_bfloat16 h[8]; u32x4 u; } pk;
  pk.h[0] = __float2bfloat16(a0); pk.h[1] = __float2bfloat16(a1);
  pk.h[2] = __float2bfloat16(a2); pk.h[3] = __float2bfloat16(a3);
  pk.h[4] = __float2bfloat16(a4); pk.h[5] = __float2bfloat16(a5);
  pk.h[6] = __float2bfloat16(a6); pk.h[7] = __float2bfloat16(a7);
  __builtin_nontemporal_store(pk.u, (u32x4*)(ag + (long)d * DIM + lane16 * 8));
}

// ---------------------------------------------------------------------------
// Layer GEMM: bf16 node state, A-frags direct from global, B in LDS.
__global__ __launch_bounds__(256, 4) void lgemm_kernel(
    const __hip_bfloat16* __restrict__ xbSelf,
    const __hip_bfloat16* __restrict__ ag0,
    const __hip_bfloat16* __restrict__ ag1,
    const __hip_bfloat16* __restrict__ ag2,
    const __hip_bfloat16* __restrict__ WT,
    const float* __restrict__ bs_t,
    const float* __restrict__ bk_t,
    const float* __restrict__ epsp,
    __hip_bfloat16* __restrict__ xnb,   // bf16 out (layers 0/1)
    float* __restrict__ xn,             // f32 out (final layer) or null
    int t) {
  __shared__ __hip_bfloat16 b_lds[128 * LDS_STRIDE];  // 34816 B

  int tid = threadIdx.x;
  long row0 = (long)blockIdx.x * 64;
  int wave = tid >> 6, lane = tid & 63;
  int l15 = lane & 15, q = lane >> 4;
  long arow = row0 + wave * 16 + l15;

  const __hip_bfloat16* Asrc[4] = {xbSelf, ag0, ag1, ag2};
  f32x4 out[8];

  for (int p = 0; p <= t + 1; ++p) {
    if (p > 0) __syncthreads();
    const __hip_bfloat16* Am = Asrc[p];
    uint4 af[4];
#pragma unroll
    for (int k0i = 0; k0i < 4; ++k0i)
      af[k0i] = *(const uint4*)(Am + arow * DIM + k0i * 32 + 8 * q);
    const __hip_bfloat16* W = (p == 0) ? (WT + (long)t * 16384)
                                       : (WT + (long)(3 + t * 3 + (p - 1)) * 16384);
    {
      const uint4* bq = (const uint4*)W;
#pragma unroll
      for (int i = 0; i < 8; ++i) {
        int idx = tid + 256 * i;
        int n = idx >> 4, k8 = idx & 15;
        uint4 v = bq[idx];
        *(uint4*)(b_lds + n * LDS_STRIDE + k8 * 8) = v;
      }
    }
    __syncthreads();

    f32x4 acc[8] = {};
#pragma unroll
    for (int k0i = 0; k0i < 4; ++k0i) {
      bf16x8 a = __builtin_bit_cast(bf16x8, af[k0i]);
#pragma unroll
      for (int j = 0; j < 8; ++j) {
        bf16x8 bfr = *(const bf16x8*)(b_lds + (16 * j + l15) * LDS_STRIDE + k0i * 32 + 8 * q);
        acc[j] = __builtin_amdgcn_mfma_f32_16x16x32_bf16(a, bfr, acc[j], 0, 0, 0);
      }
    }
    if (p == 0) {
      float sc = 1.0f + *epsp;
#pragma unroll
      for (int j = 0; j < 8; ++j) {
        float b = bs_t[16 * j + l15];
#pragma unroll
        for (int r = 0; r < 4; ++r) out[j][r] = sc * fmaxf(acc[j][r] + b, 0.f);
      }
    } else {
      const float* bb = bk_t + (p - 1) * 128;
#pragma unroll
      for (int j = 0; j < 8; ++j) {
        float b = bb[16 * j + l15];
#pragma unroll
        for (int r = 0; r < 4; ++r) out[j][r] += fmaxf(acc[j][r] + b, 0.f);
      }
    }
  }

  long rbase = row0 + wave * 16 + q * 4;
  bool fin = (xn != nullptr);
#pragma unroll
  for (int j = 0; j < 8; ++j) {
    int col = 16 * j + l15;
#pragma unroll
    for (int r = 0; r < 4; ++r) {
      long grow = rbase + r;
      if (grow < NODES) {
        float res = __bfloat162float(xbSelf[grow * DIM + col]);
        float v = res + fmaxf(out[j][r], 0.f);
        if (fin) xn[grow * DIM + col] = v;
        else     xnb[grow * DIM + col] = __float2bfloat16(v);
      }
    }
  }
}

// ---------------------------------------------------------------------------
extern "C" void kernel_launch(void* const* d_in, const int* in_sizes, int n_in,
                              void* d_out, int out_size, void* d_ws, size_t ws_size,
                              hipStream_t stream) {
  const float* x    = (const float*)d_in[0];
  const int*   ei   = (const int*)d_in[1];
  const int*   attr = (const int*)d_in[2];
  const float* Ws   = (const float*)d_in[3];
  const float* bs   = (const float*)d_in[4];
  const float* Wk   = (const float*)d_in[5];
  const float* bk   = (const float*)d_in[6];
  const float* eps  = (const float*)d_in[7];
  float* out = (float*)d_out;

  char* ws = (char*)d_ws;
  size_t off = 0;
  auto alloc = [&](size_t bytes) { char* p = ws + off; off += (bytes + 255) & ~(size_t)255; return p; };
  const size_t ROWB = (size_t)NROWP * DIM * 2;
  __hip_bfloat16* xb0  = (__hip_bfloat16*)alloc(ROWB);
  __hip_bfloat16* xb1  = (__hip_bfloat16*)alloc(ROWB);
  __hip_bfloat16* xb2  = (__hip_bfloat16*)alloc(ROWB);
  __hip_bfloat16* agA0 = (__hip_bfloat16*)alloc(ROWB);
  __hip_bfloat16* agA1 = (__hip_bfloat16*)alloc(ROWB);
  __hip_bfloat16* agA2 = (__hip_bfloat16*)alloc(ROWB);
  __hip_bfloat16* agB0 = (__hip_bfloat16*)alloc(ROWB);
  __hip_bfloat16* agB1 = (__hip_bfloat16*)alloc(ROWB);
  __hip_bfloat16* agC0 = (__hip_bfloat16*)alloc(ROWB);
  __hip_bfloat16* WT   = (__hip_bfloat16*)alloc(12 * 16384 * 2);
  int* cursor    = (int*)alloc((size_t)NB3 * 4);
  int* rowptr    = (int*)alloc((size_t)(NB3 + 1) * 4);
  int* blocksums = (int*)alloc(1024 * 4);
  int* G         = (int*)alloc((size_t)SORTN * 4);
  int* bsum2     = (int*)alloc(1024 * 4);
  int* wl        = (int*)alloc((size_t)NB3 * 4);
  int* csr_src   = (int*)alloc((size_t)(EDGES + 4 * NB3 + 16) * 4);

  int egrid  = (EDGES + 255) / 256;        // 3125
  int igrid  = (int)(ND / 4 / 256);        // 6250
  int fgrid  = (SORTN + 255) / 256;        // 221

  hipLaunchKernelGGL(init_kernel, dim3(igrid), dim3(256), 0, stream,
                     x, Ws, Wk, xb0, xb1, xb2, WT, cursor);
  hipLaunchKernelGGL(hist_kernel, dim3(egrid), dim3(256), 0, stream, ei, attr, cursor, EDGES);
  hipLaunchKernelGGL(scan_a_kernel, dim3(NBLKS), dim3(256), 0, stream, cursor, rowptr, blocksums, NB3);
  hipLaunchKernelGGL(scan_b_kernel, dim3(1), dim3(256), 0, stream, blocksums, NBLKS);
  hipLaunchKernelGGL(scanc_bhist_kernel, dim3(NBLKS), dim3(256), 0, stream,
                     rowptr, cursor, blocksums, csr_src, G, NB3);
  hipLaunchKernelGGL(fill_kernel, dim3(egrid * NPART), dim3(256), 0, stream, ei, attr, cursor, csr_src, EDGES);
  hipLaunchKernelGGL(fscan_a_kernel, dim3(fgrid), dim3(256), 0, stream, G, G, bsum2, SORTN);
  hipLaunchKernelGGL(scan_b_kernel, dim3(1), dim3(256), 0, stream, bsum2, fgrid);
  hipLaunchKernelGGL(bfill_kernel, dim3(NBLKS), dim3(256), 0, stream, rowptr, G, bsum2, wl);

  int ggrid = (NODES + 63) / 64;
  auto glaunch = [&](int nwork, const __hip_bfloat16* src, __hip_bfloat16* a0,
                     __hip_bfloat16* a1, __hip_bfloat16* a2) {
    int blocks = (nwork * 16 + 255) / 256;
    hipLaunchKernelGGL(gather_kernel, dim3(blocks), dim3(256), 0, stream,
                       src, rowptr, csr_src, wl, a0, a1, a2, nwork);
  };

  // Gather A: all buckets from xb0.
  glaunch(3 * NODES, xb0, agA0, agA1, agA2);
  // Layer 0
  hipLaunchKernelGGL(lgemm_kernel, dim3(ggrid), dim3(256), 0, stream,
                     xb0, agA0, agA0, agA0, WT, bs + 0, bk + 0, eps + 0,
                     xb1, (float*)nullptr, 0);
  // Gather B: km1 in {0,1} from xb1.
  glaunch(2 * NODES, xb1, agB0, agB1, agB1);
  // Layer 1
  hipLaunchKernelGGL(lgemm_kernel, dim3(ggrid), dim3(256), 0, stream,
                     xb1, agB0, agA1, agA1, WT, bs + 128, bk + 3 * 128, eps + 1,
                     xb2, (float*)nullptr, 1);
  // Gather C: km1=0 from xb2.
  glaunch(NODES, xb2, agC0, agC0, agC0);
  // Layer 2
  hipLaunchKernelGGL(lgemm_kernel, dim3(ggrid), dim3(256), 0, stream,
                     xb2, agC0, agB1, agA2, WT, bs + 256, bk + 6 * 128, eps + 2,
                     (__hip_bfloat16*)nullptr, out, 2);
}